// Round 5
// baseline (455.864 us; speedup 1.0000x reference)
//
#include <hip/hip_runtime.h>
#include <math.h>

#define BATCH 256
#define PRE   64     // k
#define NEXT  32     // K
#define DIN   128    // d
#define DOUT  64     // D

typedef __attribute__((ext_vector_type(8))) short bf16x8;
typedef __attribute__((ext_vector_type(4))) float f32x4;

__device__ __forceinline__ unsigned short f2bf(float f) {
    unsigned u = __float_as_uint(f);
    unsigned r = (u + 0x7fffu + ((u >> 16) & 1u)) >> 16;   // RNE
    return (unsigned short)r;
}
__device__ __forceinline__ float bf2f(unsigned short h) {
    return __uint_as_float(((unsigned)h) << 16);
}

// ---------------- pack: W fp32 [k,K,d,D] -> Wh/Wl bf16, MFMA-fragment order ----
// frag idx = (((Kk*4+dc)*4+nt)*4+quad)*16+ln, vec8 over j; d = dc*32+quad*8+j,
// D = nt*16+ln. Layout verified against round-3's (passing) inline B gather.
__global__ __launch_bounds__(256) void pack_kernel(const float* __restrict__ W,
                                                   short* __restrict__ Wh,
                                                   short* __restrict__ Wl)
{
    const int tau  = blockIdx.x * 256 + threadIdx.x;   // 0..2^21-1
    const int ln   = tau & 15;
    const int quad = (tau >> 4) & 3;
    const int nt   = (tau >> 6) & 3;
    const int dc   = (tau >> 8) & 3;
    const int Kk   = tau >> 10;                        // kk*32 + K
    const float* src = W + ((size_t)Kk * DIN + dc * 32 + quad * 8) * DOUT + nt * 16 + ln;
    bf16x8 hv, lv;
#pragma unroll
    for (int j = 0; j < 8; ++j) {
        float v = src[(size_t)j * DOUT];
        unsigned short h = f2bf(v);
        hv[j] = (short)h;
        lv[j] = (short)f2bf(v - bf2f(h));
    }
    *(bf16x8*)(Wh + (size_t)tau * 8) = hv;
    *(bf16x8*)(Wl + (size_t)tau * 8) = lv;
}

// ---------------- MFMA GEMM -> p fp32, NATURAL [lb,k,K,D] layout --------------
// Grid (K=32, k=64, bt=chunk/128), 256 thr = 4 waves, wave = 32 b-rows.
// 3-product split (xh*wh + xl*wh + xh*wl); identical numerics to round 3 (passed).
// B frags: one 16B load each from pre-packed Wh/Wl (round-3's VALU sink removed).
__global__ __launch_bounds__(256, 2) void gemm_kernel(const float* __restrict__ x,
                                                      const short* __restrict__ Wh,
                                                      const short* __restrict__ Wl,
                                                      float* __restrict__ p,
                                                      int b0)
{
    const int K    = blockIdx.x;
    const int kk   = blockIdx.y;
    const int bt   = blockIdx.z;
    const int t    = threadIdx.x;
    const int wave = t >> 6;
    const int lane = t & 63;
    const int ln   = lane & 15;
    const int quad = lane >> 4;
    const int row0 = bt * 128 + wave * 32;   // local row base within chunk

    f32x4 acc[2][4];
#pragma unroll
    for (int mt = 0; mt < 2; ++mt)
#pragma unroll
        for (int nt = 0; nt < 4; ++nt) acc[mt][nt] = (f32x4){0.f, 0.f, 0.f, 0.f};

    const size_t fragKK = (size_t)(kk * NEXT + K) * 1024;

    for (int dc = 0; dc < 4; ++dc) {
        const int d0 = dc * 32 + quad * 8;
        // A fragments (x), in-kernel hi/lo split (cheap: 16 elems/thread)
        bf16x8 ah[2], al[2];
#pragma unroll
        for (int mt = 0; mt < 2; ++mt) {
            const float* xa = x + ((size_t)(b0 + row0 + mt * 16 + ln) * PRE + kk) * DIN + d0;
            float4 v0 = *(const float4*)xa;
            float4 v1 = *(const float4*)(xa + 4);
            float xv[8] = {v0.x, v0.y, v0.z, v0.w, v1.x, v1.y, v1.z, v1.w};
#pragma unroll
            for (int j = 0; j < 8; ++j) {
                unsigned short h = f2bf(xv[j]);
                ah[mt][j] = (short)h;
                al[mt][j] = (short)f2bf(xv[j] - bf2f(h));
            }
        }
        // B fragments: single 16B loads from packed arrays
        bf16x8 bh[4], bl[4];
#pragma unroll
        for (int nt = 0; nt < 4; ++nt) {
            const size_t idx = (fragKK + dc * 256 + nt * 64 + quad * 16 + ln) * 8;
            bh[nt] = *(const bf16x8*)(Wh + idx);
            bl[nt] = *(const bf16x8*)(Wl + idx);
        }
#pragma unroll
        for (int mt = 0; mt < 2; ++mt)
#pragma unroll
            for (int nt = 0; nt < 4; ++nt) {
                acc[mt][nt] = __builtin_amdgcn_mfma_f32_16x16x32_bf16(ah[mt], bh[nt], acc[mt][nt], 0, 0, 0);
                acc[mt][nt] = __builtin_amdgcn_mfma_f32_16x16x32_bf16(al[mt], bh[nt], acc[mt][nt], 0, 0, 0);
                acc[mt][nt] = __builtin_amdgcn_mfma_f32_16x16x32_bf16(ah[mt], bl[nt], acc[mt][nt], 0, 0, 0);
            }
    }

    // store natural fp32: C/D map col=ln, row=quad*4+r; 16 ln-lanes = 64B lines
#pragma unroll
    for (int mt = 0; mt < 2; ++mt)
#pragma unroll
        for (int nt = 0; nt < 4; ++nt) {
            const int D = nt * 16 + ln;
#pragma unroll
            for (int r = 0; r < 4; ++r) {
                const int row = row0 + mt * 16 + quad * 4 + r;
                p[((size_t)(row * PRE + kk) * NEXT + K) * DOUT + D] = acc[mt][nt][r];
            }
        }
}

// ---------------- Routing: 3 fused passes over fp32 p (round-3 math) ----------
// 512 thr = 8 waves per b; wave w: k = i*8+w, i=0..7. Load j: float4 idx
// j*64+lane -> K = j*4+(lane>>4), chunk m = lane&15 -> 1KB coalesced per inst.
// D-dot: shfl xor 1,2,4,8 (m). Softmax over K: 8 j-regs + shfl xor 16,32 (g).
// Cross-wave q: per-wave LDS region + tree sum (no atomics, no conflicts).
// (512,2) -> 256-VGPR budget for ~210 live regs: NO spill (R3/R4 lesson).
__global__ __launch_bounds__(512, 2) void route_kernel(const float* __restrict__ p,
                                                       float* __restrict__ out,
                                                       int b0)
{
    __shared__ float qpart[8 * 2048];   // 64 KB: [wave][K][D]
    const int b    = blockIdx.x;
    const int t    = threadIdx.x;
    const int w    = t >> 6;
    const int lane = t & 63;
    const int g    = lane >> 4;   // 0..3
    const int m    = lane & 15;   // 0..15
    const float4* pb = (const float4*)(p + (size_t)b * (PRE * NEXT * DOUT));

    float4 qc[8], qa[8];          // q current / accumulator: K=j*4+g, D=m*4..+3
    float blog[8][8];             // [i][j] logits, persists across passes
#pragma unroll
    for (int i = 0; i < 8; ++i)
#pragma unroll
        for (int j = 0; j < 8; ++j) blog[i][j] = 0.f;

    for (int pass = 0; pass < 3; ++pass) {
#pragma unroll
        for (int j = 0; j < 8; ++j) qa[j] = (float4){0.f, 0.f, 0.f, 0.f};

        float4 pv[2][8];
        {
            const size_t sb = (size_t)w * 512;
#pragma unroll
            for (int j = 0; j < 8; ++j) pv[0][j] = pb[sb + j * 64 + lane];
        }
#pragma unroll
        for (int i = 0; i < 8; ++i) {
            const int buf = i & 1;
            if (i < 7) {
                const size_t sb = (size_t)((i + 1) * 8 + w) * 512;
#pragma unroll
                for (int j = 0; j < 8; ++j) pv[buf ^ 1][j] = pb[sb + j * 64 + lane];
            }
            float c[8];
            if (pass == 0) {
#pragma unroll
                for (int j = 0; j < 8; ++j) c[j] = 1.0f / 32.0f;
            } else {
#pragma unroll
                for (int j = 0; j < 8; ++j) {
                    float d = pv[buf][j].x * qc[j].x + pv[buf][j].y * qc[j].y
                            + pv[buf][j].z * qc[j].z + pv[buf][j].w * qc[j].w;
                    d += __shfl_xor(d, 1);
                    d += __shfl_xor(d, 2);
                    d += __shfl_xor(d, 4);
                    d += __shfl_xor(d, 8);
                    blog[i][j] += d;
                }
                float mx = blog[i][0];
#pragma unroll
                for (int j = 1; j < 8; ++j) mx = fmaxf(mx, blog[i][j]);
                mx = fmaxf(mx, __shfl_xor(mx, 16));
                mx = fmaxf(mx, __shfl_xor(mx, 32));
                float s = 0.f;
#pragma unroll
                for (int j = 0; j < 8; ++j) { c[j] = __expf(blog[i][j] - mx); s += c[j]; }
                s += __shfl_xor(s, 16);
                s += __shfl_xor(s, 32);
                float inv = 1.0f / s;
#pragma unroll
                for (int j = 0; j < 8; ++j) c[j] *= inv;
            }
#pragma unroll
            for (int j = 0; j < 8; ++j) {
                qa[j].x += c[j] * pv[buf][j].x;
                qa[j].y += c[j] * pv[buf][j].y;
                qa[j].z += c[j] * pv[buf][j].z;
                qa[j].w += c[j] * pv[buf][j].w;
            }
        }
        // per-wave partial q -> LDS (contiguous b128, conflict-free)
#pragma unroll
        for (int j = 0; j < 8; ++j)
            *(float4*)&qpart[w * 2048 + (j * 4 + g) * 64 + m * 4] = qa[j];
        __syncthreads();

        // tree-sum over waves + squash; thread t owns (K=t>>4, ch=t&15)
        {
            const int Kq = t >> 4, ch = t & 15;
            float4 v = (float4){0.f, 0.f, 0.f, 0.f};
#pragma unroll
            for (int ww = 0; ww < 8; ++ww) {
                float4 s4 = *(const float4*)&qpart[ww * 2048 + Kq * 64 + ch * 4];
                v.x += s4.x; v.y += s4.y; v.z += s4.z; v.w += s4.w;
            }
            float s2 = v.x * v.x + v.y * v.y + v.z * v.z + v.w * v.w;
            s2 += __shfl_xor(s2, 1);
            s2 += __shfl_xor(s2, 2);
            s2 += __shfl_xor(s2, 4);
            s2 += __shfl_xor(s2, 8);
            float fsc = s2 / ((1.f + s2) * sqrtf(s2 + 1e-8f));
            v.x *= fsc; v.y *= fsc; v.z *= fsc; v.w *= fsc;
            if (pass < 2) {
                *(float4*)&qpart[Kq * 64 + ch * 4] = v;   // region 0 = final q
            } else {
                *(float4*)(out + (size_t)(b0 + b) * 2048 + Kq * 64 + ch * 4) = v;
            }
        }
        if (pass < 2) {
            __syncthreads();
#pragma unroll
            for (int j = 0; j < 8; ++j)
                qc[j] = *(const float4*)&qpart[(j * 4 + g) * 64 + m * 4];
            __syncthreads();   // protect region 0 before next pass's stores
        }
    }
}

extern "C" void kernel_launch(void* const* d_in, const int* in_sizes, int n_in,
                              void* d_out, int out_size, void* d_ws, size_t ws_size,
                              hipStream_t stream) {
    const float* x = (const float*)d_in[0];
    const float* W = (const float*)d_in[1];
    float* out = (float*)d_out;

    // ws carve: Wh 32 MiB | Wl 32 MiB | p fp32 (full 128 MiB if ws allows,
    // else 2 chunks of 64 MiB -> total exactly the 128 MiB every passing
    // round already used)
    short* Wh = (short*)d_ws;
    short* Wl = (short*)((char*)d_ws + 33554432);
    float* p  = (float*)((char*)d_ws + 67108864);

    const int chunk = (ws_size >= (size_t)67108864 + 134217728) ? 256 : 128;

    pack_kernel<<<8192, 256, 0, stream>>>(W, Wh, Wl);
    for (int b0 = 0; b0 < BATCH; b0 += chunk) {
        gemm_kernel<<<dim3(NEXT, PRE, chunk / 128), 256, 0, stream>>>(x, Wh, Wl, p, b0);
        route_kernel<<<chunk, 512, 0, stream>>>(p, out, b0);
    }
}

// Round 6
// 320.039 us; speedup vs baseline: 1.4244x; 1.4244x over previous
//
#include <hip/hip_runtime.h>
#include <math.h>

#define BATCH 256
#define PRE   64     // k
#define NEXT  32     // K
#define DIN   128    // d
#define DOUT  64     // D

typedef __attribute__((ext_vector_type(8))) short bf16x8;
typedef __attribute__((ext_vector_type(4))) float f32x4;

__device__ __forceinline__ unsigned short f2bf(float f) {
    unsigned u = __float_as_uint(f);
    unsigned r = (u + 0x7fffu + ((u >> 16) & 1u)) >> 16;   // RNE
    return (unsigned short)r;
}
__device__ __forceinline__ float bf2f(unsigned short h) {
    return __uint_as_float(((unsigned)h) << 16);
}

// ---------------- pack: W fp32 [k,K,d,D] -> Wh/Wl bf16, MFMA-fragment order ----
// frag idx = (((Kk*4+dc)*4+nt)*4+quad)*16+ln, vec8 over j; d = dc*32+quad*8+j,
// D = nt*16+ln. (Unchanged from round 5 — passed.)
__global__ __launch_bounds__(256) void pack_kernel(const float* __restrict__ W,
                                                   short* __restrict__ Wh,
                                                   short* __restrict__ Wl)
{
    const int tau  = blockIdx.x * 256 + threadIdx.x;   // 0..2^21-1
    const int ln   = tau & 15;
    const int quad = (tau >> 4) & 3;
    const int nt   = (tau >> 6) & 3;
    const int dc   = (tau >> 8) & 3;
    const int Kk   = tau >> 10;                        // kk*32 + K
    const float* src = W + ((size_t)Kk * DIN + dc * 32 + quad * 8) * DOUT + nt * 16 + ln;
    bf16x8 hv, lv;
#pragma unroll
    for (int j = 0; j < 8; ++j) {
        float v = src[(size_t)j * DOUT];
        unsigned short h = f2bf(v);
        hv[j] = (short)h;
        lv[j] = (short)f2bf(v - bf2f(h));
    }
    *(bf16x8*)(Wh + (size_t)tau * 8) = hv;
    *(bf16x8*)(Wl + (size_t)tau * 8) = lv;
}

// ---------------- MFMA GEMM -> p fp32, NATURAL [lb,k,K,D] layout --------------
// Grid (K=32, k=64, bt=chunk/128), 256 thr = 4 waves, wave = 32 b-rows.
// 3-product split (xh*wh + xl*wh + xh*wl). NEW: x-tile staged via LDS so the
// A-fragment read is coalesced (previously a 16-line gather per instruction).
// LDS row stride 40 floats: 160B per row -> float4-aligned; fragment-read bank
// aliasing = 4-way (1.58x on 4 LDS instrs/dc = negligible).
__global__ __launch_bounds__(256, 2) void gemm_kernel(const float* __restrict__ x,
                                                      const short* __restrict__ Wh,
                                                      const short* __restrict__ Wl,
                                                      float* __restrict__ p,
                                                      int b0)
{
    __shared__ float xs[128 * 40];   // 20.5 KB: [row][d] for current dc chunk
    const int K    = blockIdx.x;
    const int kk   = blockIdx.y;
    const int bt   = blockIdx.z;
    const int t    = threadIdx.x;
    const int wave = t >> 6;
    const int lane = t & 63;
    const int ln   = lane & 15;
    const int quad = lane >> 4;
    const int row0 = bt * 128 + wave * 32;   // local (chunk) row base

    f32x4 acc[2][4];
#pragma unroll
    for (int mt = 0; mt < 2; ++mt)
#pragma unroll
        for (int nt = 0; nt < 4; ++nt) acc[mt][nt] = (f32x4){0.f, 0.f, 0.f, 0.f};

    const size_t fragKK = (size_t)(kk * NEXT + K) * 1024;

    for (int dc = 0; dc < 4; ++dc) {
        __syncthreads();
        // stage x tile: 128 rows x 32 d, 128B-contiguous per row per wave-instr
#pragma unroll
        for (int i = 0; i < 4; ++i) {
            const int f   = t + 256 * i;    // 0..1023 float4s
            const int row = f >> 3;
            const int d4  = f & 7;
            float4 v = *(const float4*)(x + ((size_t)(b0 + bt * 128 + row) * PRE + kk) * DIN + dc * 32 + d4 * 4);
            *(float4*)&xs[row * 40 + d4 * 4] = v;
        }
        __syncthreads();

        // A fragments from LDS + hi/lo split
        bf16x8 ah[2], al[2];
#pragma unroll
        for (int mt = 0; mt < 2; ++mt) {
            const float* xa = &xs[(wave * 32 + mt * 16 + ln) * 40 + quad * 8];
            float4 v0 = *(const float4*)xa;
            float4 v1 = *(const float4*)(xa + 4);
            float xv[8] = {v0.x, v0.y, v0.z, v0.w, v1.x, v1.y, v1.z, v1.w};
#pragma unroll
            for (int j = 0; j < 8; ++j) {
                unsigned short h = f2bf(xv[j]);
                ah[mt][j] = (short)h;
                al[mt][j] = (short)f2bf(xv[j] - bf2f(h));
            }
        }
        // B fragments: single 16B loads from packed arrays
        bf16x8 bh[4], bl[4];
#pragma unroll
        for (int nt = 0; nt < 4; ++nt) {
            const size_t idx = (fragKK + dc * 256 + nt * 64 + quad * 16 + ln) * 8;
            bh[nt] = *(const bf16x8*)(Wh + idx);
            bl[nt] = *(const bf16x8*)(Wl + idx);
        }
#pragma unroll
        for (int mt = 0; mt < 2; ++mt)
#pragma unroll
            for (int nt = 0; nt < 4; ++nt) {
                acc[mt][nt] = __builtin_amdgcn_mfma_f32_16x16x32_bf16(ah[mt], bh[nt], acc[mt][nt], 0, 0, 0);
                acc[mt][nt] = __builtin_amdgcn_mfma_f32_16x16x32_bf16(al[mt], bh[nt], acc[mt][nt], 0, 0, 0);
                acc[mt][nt] = __builtin_amdgcn_mfma_f32_16x16x32_bf16(ah[mt], bl[nt], acc[mt][nt], 0, 0, 0);
            }
    }

    // store natural fp32: C/D map col=ln, row=quad*4+r; 16 ln-lanes = 64B lines
#pragma unroll
    for (int mt = 0; mt < 2; ++mt)
#pragma unroll
        for (int nt = 0; nt < 4; ++nt) {
            const int D = nt * 16 + ln;
#pragma unroll
            for (int r = 0; r < 4; ++r) {
                const int row = row0 + mt * 16 + quad * 4 + r;
                p[((size_t)(row * PRE + kk) * NEXT + K) * DOUT + D] = acc[mt][nt][r];
            }
        }
}

// ---------------- Routing: 3 fused passes over fp32 p -------------------------
// KEY CHANGE: b is linear in q => logits_t = p . (q1+...+q_{t-1}). Keep only the
// running sum Q in registers; blog[8][8] (64 VGPRs) eliminated -> ~150 live regs.
// __launch_bounds__(512,1): second arg is min BLOCKS/CU on this toolchain
// (R3/R5 evidence) -> no VGPR cap, no spill; 256 blocks on 256 CUs = 1/CU anyway.
// 512 thr = 8 waves per b; wave w: k = i*8+w. Load j: float4 idx j*64+lane ->
// K = j*4+(lane>>4), chunk m = lane&15 -> 1KB coalesced per instruction.
// D-dot: shfl xor 1,2,4,8. Softmax over K: 8 j-regs + shfl xor 16,32.
__global__ __launch_bounds__(512, 1) void route_kernel(const float* __restrict__ p,
                                                       float* __restrict__ out,
                                                       int b0)
{
    __shared__ float qpart[8 * 2048];   // 64 KB: [wave][K][D]
    const int b    = blockIdx.x;
    const int t    = threadIdx.x;
    const int w    = t >> 6;
    const int lane = t & 63;
    const int g    = lane >> 4;   // 0..3
    const int m    = lane & 15;   // 0..15
    const float4* pb = (const float4*)(p + (size_t)b * (PRE * NEXT * DOUT));

    float4 qs[8];                 // running sum Q = q1+..+q_{t-1}: K=j*4+g, D=m*4..+3
#pragma unroll
    for (int j = 0; j < 8; ++j) qs[j] = (float4){0.f, 0.f, 0.f, 0.f};

    for (int pass = 0; pass < 3; ++pass) {
        float4 qa[8];
#pragma unroll
        for (int j = 0; j < 8; ++j) qa[j] = (float4){0.f, 0.f, 0.f, 0.f};

        float4 pv[2][8];
        {
            const size_t sb = (size_t)w * 512;
#pragma unroll
            for (int j = 0; j < 8; ++j) pv[0][j] = pb[sb + j * 64 + lane];
        }
#pragma unroll
        for (int i = 0; i < 8; ++i) {
            const int buf = i & 1;
            if (i < 7) {
                const size_t sb = (size_t)((i + 1) * 8 + w) * 512;
#pragma unroll
                for (int j = 0; j < 8; ++j) pv[buf ^ 1][j] = pb[sb + j * 64 + lane];
            }
            float c[8];
            if (pass == 0) {
#pragma unroll
                for (int j = 0; j < 8; ++j) c[j] = 1.0f / 32.0f;
            } else {
                // logits = p . Q (running sum) — replaces persistent blog
#pragma unroll
                for (int j = 0; j < 8; ++j) {
                    float d = pv[buf][j].x * qs[j].x + pv[buf][j].y * qs[j].y
                            + pv[buf][j].z * qs[j].z + pv[buf][j].w * qs[j].w;
                    d += __shfl_xor(d, 1);
                    d += __shfl_xor(d, 2);
                    d += __shfl_xor(d, 4);
                    d += __shfl_xor(d, 8);
                    c[j] = d;   // logit for K=j*4+g
                }
                float mx = c[0];
#pragma unroll
                for (int j = 1; j < 8; ++j) mx = fmaxf(mx, c[j]);
                mx = fmaxf(mx, __shfl_xor(mx, 16));
                mx = fmaxf(mx, __shfl_xor(mx, 32));
                float s = 0.f;
#pragma unroll
                for (int j = 0; j < 8; ++j) { c[j] = __expf(c[j] - mx); s += c[j]; }
                s += __shfl_xor(s, 16);
                s += __shfl_xor(s, 32);
                float inv = 1.0f / s;
#pragma unroll
                for (int j = 0; j < 8; ++j) c[j] *= inv;
            }
#pragma unroll
            for (int j = 0; j < 8; ++j) {
                qa[j].x += c[j] * pv[buf][j].x;
                qa[j].y += c[j] * pv[buf][j].y;
                qa[j].z += c[j] * pv[buf][j].z;
                qa[j].w += c[j] * pv[buf][j].w;
            }
        }
        // per-wave partial q -> LDS (contiguous b128, conflict-free)
#pragma unroll
        for (int j = 0; j < 8; ++j)
            *(float4*)&qpart[w * 2048 + (j * 4 + g) * 64 + m * 4] = qa[j];
        __syncthreads();

        // tree-sum over waves + squash; thread t owns (K=t>>4, ch=t&15)
        {
            const int Kq = t >> 4, ch = t & 15;
            float4 v = (float4){0.f, 0.f, 0.f, 0.f};
#pragma unroll
            for (int ww = 0; ww < 8; ++ww) {
                float4 s4 = *(const float4*)&qpart[ww * 2048 + Kq * 64 + ch * 4];
                v.x += s4.x; v.y += s4.y; v.z += s4.z; v.w += s4.w;
            }
            float s2 = v.x * v.x + v.y * v.y + v.z * v.z + v.w * v.w;
            s2 += __shfl_xor(s2, 1);
            s2 += __shfl_xor(s2, 2);
            s2 += __shfl_xor(s2, 4);
            s2 += __shfl_xor(s2, 8);
            float fsc = s2 / ((1.f + s2) * sqrtf(s2 + 1e-8f));
            v.x *= fsc; v.y *= fsc; v.z *= fsc; v.w *= fsc;
            if (pass < 2) {
                *(float4*)&qpart[Kq * 64 + ch * 4] = v;   // region 0 := q_new
            } else {
                *(float4*)(out + (size_t)(b0 + b) * 2048 + Kq * 64 + ch * 4) = v;
            }
        }
        if (pass < 2) {
            __syncthreads();
#pragma unroll
            for (int j = 0; j < 8; ++j) {
                float4 qn = *(const float4*)&qpart[(j * 4 + g) * 64 + m * 4];
                qs[j].x += qn.x; qs[j].y += qn.y; qs[j].z += qn.z; qs[j].w += qn.w;
            }
            __syncthreads();   // protect region 0 before next pass's stores
        }
    }
}

extern "C" void kernel_launch(void* const* d_in, const int* in_sizes, int n_in,
                              void* d_out, int out_size, void* d_ws, size_t ws_size,
                              hipStream_t stream) {
    const float* x = (const float*)d_in[0];
    const float* W = (const float*)d_in[1];
    float* out = (float*)d_out;

    // ws carve: Wh 32 MiB | Wl 32 MiB | p fp32 128 MiB (192 MiB total; R5
    // confirmed available — single route dispatch per call). Fallback: 2 chunks.
    short* Wh = (short*)d_ws;
    short* Wl = (short*)((char*)d_ws + 33554432);
    float* p  = (float*)((char*)d_ws + 67108864);

    const int chunk = (ws_size >= (size_t)67108864 + 134217728) ? 256 : 128;

    pack_kernel<<<8192, 256, 0, stream>>>(W, Wh, Wl);
    for (int b0 = 0; b0 < BATCH; b0 += chunk) {
        gemm_kernel<<<dim3(NEXT, PRE, chunk / 128), 256, 0, stream>>>(x, Wh, Wl, p, b0);
        route_kernel<<<chunk, 512, 0, stream>>>(p, out, b0);
    }
}

// Round 7
// 271.971 us; speedup vs baseline: 1.6761x; 1.1767x over previous
//
#include <hip/hip_runtime.h>
#include <math.h>

#define BATCH 256
#define PRE   64     // k
#define NEXT  32     // K
#define DIN   128    // d
#define DOUT  64     // D

typedef __attribute__((ext_vector_type(8))) short bf16x8;
typedef __attribute__((ext_vector_type(4))) float f32x4;

__device__ __forceinline__ unsigned short f2bf(float f) {
    unsigned u = __float_as_uint(f);
    unsigned r = (u + 0x7fffu + ((u >> 16) & 1u)) >> 16;   // RNE
    return (unsigned short)r;
}
__device__ __forceinline__ float bf2f(unsigned short h) {
    return __uint_as_float(((unsigned)h) << 16);
}

#define WFRAG_S 10   // dwords per fragment slot (8 data + 2 pad): ln*10%32 hits
                     // 16 distinct banks -> 4-way (nt) conflicts only

// ---------------- MFMA GEMM -> p fp32, NATURAL [lb,k,K,D] layout --------------
// Grid (K=32, k=64, bt=chunk/128), 256 thr = 4 waves, wave = 32 b-rows.
// 3-product split (xh*wh + xl*wh + xh*wl). W converted to bf16 hi/lo IN-KERNEL:
// per dc chunk the block cooperatively stages its 32x64 W slab as packed
// (h | l<<16) dwords in MFMA-fragment order (8 elems/thread, ~50 VALU) -> no
// global Wh/Wl buffers -> p can own the full 128 MiB workspace.
__global__ __launch_bounds__(256, 2) void gemm_kernel(const float* __restrict__ x,
                                                      const float* __restrict__ W,
                                                      float* __restrict__ p,
                                                      int b0)
{
    __shared__ float xs[128 * 40];              // 20.5 KB x-tile [row][d]
    __shared__ unsigned wpk[256 * WFRAG_S];     // 10 KB packed W frags
    const int K    = blockIdx.x;
    const int kk   = blockIdx.y;
    const int bt   = blockIdx.z;
    const int t    = threadIdx.x;
    const int wave = t >> 6;
    const int lane = t & 63;
    const int ln   = lane & 15;
    const int quad = lane >> 4;
    const int row0 = bt * 128 + wave * 32;      // local (chunk) row base

    f32x4 acc[2][4];
#pragma unroll
    for (int mt = 0; mt < 2; ++mt)
#pragma unroll
        for (int nt = 0; nt < 4; ++nt) acc[mt][nt] = (f32x4){0.f, 0.f, 0.f, 0.f};

    const float* Wk = W + (size_t)(kk * NEXT + K) * DIN * DOUT;

    for (int dc = 0; dc < 4; ++dc) {
        __syncthreads();
        // stage x tile: 128 rows x 32 d (coalesced float4)
#pragma unroll
        for (int i = 0; i < 4; ++i) {
            const int f   = t + 256 * i;    // 0..1023 float4s
            const int row = f >> 3;
            const int d4  = f & 7;
            float4 v = *(const float4*)(x + ((size_t)(b0 + bt * 128 + row) * PRE + kk) * DIN + dc * 32 + d4 * 4);
            *(float4*)&xs[row * 40 + d4 * 4] = v;
        }
        // stage W slab 32x64, convert to packed bf16 hi|lo in fragment order
#pragma unroll
        for (int it = 0; it < 8; ++it) {
            const int e  = it * 256 + t;    // 0..2047
            const int dl = e >> 6;          // 0..31
            const int D  = e & 63;
            float v = Wk[(size_t)(dc * 32 + dl) * DOUT + D];
            unsigned short h = f2bf(v);
            unsigned short l = f2bf(v - bf2f(h));
            const int fr = ((D >> 4) * 64 + (dl >> 3) * 16 + (D & 15));
            wpk[fr * WFRAG_S + (dl & 7)] = (unsigned)h | ((unsigned)l << 16);
        }
        __syncthreads();

        // A fragments from xs + hi/lo split
        bf16x8 ah[2], al[2];
#pragma unroll
        for (int mt = 0; mt < 2; ++mt) {
            const float* xa = &xs[(wave * 32 + mt * 16 + ln) * 40 + quad * 8];
            float4 v0 = *(const float4*)xa;
            float4 v1 = *(const float4*)(xa + 4);
            float xv[8] = {v0.x, v0.y, v0.z, v0.w, v1.x, v1.y, v1.z, v1.w};
#pragma unroll
            for (int j = 0; j < 8; ++j) {
                unsigned short h = f2bf(xv[j]);
                ah[mt][j] = (short)h;
                al[mt][j] = (short)f2bf(xv[j] - bf2f(h));
            }
        }
        // B fragments from packed LDS (b64 reads, 8B-aligned at stride 40B)
        bf16x8 bh[4], bl[4];
#pragma unroll
        for (int nt = 0; nt < 4; ++nt) {
            const unsigned* wp = &wpk[(nt * 64 + quad * 16 + ln) * WFRAG_S];
            unsigned pk[8];
#pragma unroll
            for (int i2 = 0; i2 < 4; ++i2) *(uint2*)&pk[i2 * 2] = *(const uint2*)&wp[i2 * 2];
            union { bf16x8 v; unsigned u[4]; } BH, BL;
#pragma unroll
            for (int i2 = 0; i2 < 4; ++i2) {
                BH.u[i2] = (pk[2 * i2] & 0xffffu) | (pk[2 * i2 + 1] << 16);
                BL.u[i2] = (pk[2 * i2] >> 16) | (pk[2 * i2 + 1] & 0xffff0000u);
            }
            bh[nt] = BH.v; bl[nt] = BL.v;
        }
#pragma unroll
        for (int mt = 0; mt < 2; ++mt)
#pragma unroll
            for (int nt = 0; nt < 4; ++nt) {
                acc[mt][nt] = __builtin_amdgcn_mfma_f32_16x16x32_bf16(ah[mt], bh[nt], acc[mt][nt], 0, 0, 0);
                acc[mt][nt] = __builtin_amdgcn_mfma_f32_16x16x32_bf16(al[mt], bh[nt], acc[mt][nt], 0, 0, 0);
                acc[mt][nt] = __builtin_amdgcn_mfma_f32_16x16x32_bf16(ah[mt], bl[nt], acc[mt][nt], 0, 0, 0);
            }
    }

    // store natural fp32: C/D map col=ln, row=quad*4+r; 16 ln-lanes = 64B lines
#pragma unroll
    for (int mt = 0; mt < 2; ++mt)
#pragma unroll
        for (int nt = 0; nt < 4; ++nt) {
            const int D = nt * 16 + ln;
#pragma unroll
            for (int r = 0; r < 4; ++r) {
                const int row = row0 + mt * 16 + quad * 4 + r;
                p[((size_t)(row * PRE + kk) * NEXT + K) * DOUT + D] = acc[mt][nt][r];
            }
        }
}

// ---------------- Routing: 3 fused passes over fp32 p -------------------------
// One 512-thr block (8 waves) per b (full 256-block grid with chunk=256).
// Running-sum trick: logits_t = p . (q1+..+q_{t-1}); Q lives in LDS (qsum) and
// is read as b128 inside the inner loop -> 32 VGPRs saved vs registers; live
// set ~115 fits the 128 budget -> no spill (R5/R6 lesson).
// Wave w: k = i*8+w. Load j: float4 idx j*64+lane -> K = j*4+(lane>>4),
// D-chunk m = lane&15 -> every load instruction reads 1KB contiguous.
__global__ __launch_bounds__(512, 1) void route_kernel(const float* __restrict__ p,
                                                       float* __restrict__ out,
                                                       int b0)
{
    __shared__ float qpart[8 * 2048];   // 64 KB per-wave partial q
    __shared__ float qsum[2048];        // 8 KB running Q = q1+..+q_{t-1}
    const int b    = blockIdx.x;
    const int t    = threadIdx.x;
    const int w    = t >> 6;
    const int lane = t & 63;
    const int g    = lane >> 4;   // 0..3
    const int m    = lane & 15;   // 0..15
    const float4* pb = (const float4*)(p + (size_t)b * (PRE * NEXT * DOUT));

    for (int idx = t; idx < 2048; idx += 512) qsum[idx] = 0.f;
    __syncthreads();

    for (int pass = 0; pass < 3; ++pass) {
        float4 qa[8];
#pragma unroll
        for (int j = 0; j < 8; ++j) qa[j] = (float4){0.f, 0.f, 0.f, 0.f};

        float4 pv[2][8];
        {
            const size_t sb = (size_t)w * 512;
#pragma unroll
            for (int j = 0; j < 8; ++j) pv[0][j] = pb[sb + j * 64 + lane];
        }
#pragma unroll
        for (int i = 0; i < 8; ++i) {
            const int buf = i & 1;
            if (i < 7) {
                const size_t sb = (size_t)((i + 1) * 8 + w) * 512;
#pragma unroll
                for (int j = 0; j < 8; ++j) pv[buf ^ 1][j] = pb[sb + j * 64 + lane];
            }
            float c[8];
            if (pass == 0) {
#pragma unroll
                for (int j = 0; j < 8; ++j) c[j] = 1.0f / 32.0f;
            } else {
                // logits = p . Q, Q streamed from LDS (b128, 16B-aligned)
#pragma unroll
                for (int j = 0; j < 8; ++j) {
                    float4 qv = *(const float4*)&qsum[(j * 4 + g) * 64 + m * 4];
                    float d = pv[buf][j].x * qv.x + pv[buf][j].y * qv.y
                            + pv[buf][j].z * qv.z + pv[buf][j].w * qv.w;
                    d += __shfl_xor(d, 1);
                    d += __shfl_xor(d, 2);
                    d += __shfl_xor(d, 4);
                    d += __shfl_xor(d, 8);
                    c[j] = d;
                }
                float mx = c[0];
#pragma unroll
                for (int j = 1; j < 8; ++j) mx = fmaxf(mx, c[j]);
                mx = fmaxf(mx, __shfl_xor(mx, 16));
                mx = fmaxf(mx, __shfl_xor(mx, 32));
                float s = 0.f;
#pragma unroll
                for (int j = 0; j < 8; ++j) { c[j] = __expf(c[j] - mx); s += c[j]; }
                s += __shfl_xor(s, 16);
                s += __shfl_xor(s, 32);
                float inv = 1.0f / s;
#pragma unroll
                for (int j = 0; j < 8; ++j) c[j] *= inv;
            }
#pragma unroll
            for (int j = 0; j < 8; ++j) {
                qa[j].x += c[j] * pv[buf][j].x;
                qa[j].y += c[j] * pv[buf][j].y;
                qa[j].z += c[j] * pv[buf][j].z;
                qa[j].w += c[j] * pv[buf][j].w;
            }
        }
        // per-wave partial q -> LDS (contiguous b128, conflict-free)
#pragma unroll
        for (int j = 0; j < 8; ++j)
            *(float4*)&qpart[w * 2048 + (j * 4 + g) * 64 + m * 4] = qa[j];
        __syncthreads();

        // tree-sum over waves + squash; thread t owns (K=t>>4, ch=t&15)
        {
            const int Kq = t >> 4, ch = t & 15;
            float4 v = (float4){0.f, 0.f, 0.f, 0.f};
#pragma unroll
            for (int ww = 0; ww < 8; ++ww) {
                float4 s4 = *(const float4*)&qpart[ww * 2048 + Kq * 64 + ch * 4];
                v.x += s4.x; v.y += s4.y; v.z += s4.z; v.w += s4.w;
            }
            float s2 = v.x * v.x + v.y * v.y + v.z * v.z + v.w * v.w;
            s2 += __shfl_xor(s2, 1);
            s2 += __shfl_xor(s2, 2);
            s2 += __shfl_xor(s2, 4);
            s2 += __shfl_xor(s2, 8);
            float fsc = s2 / ((1.f + s2) * sqrtf(s2 + 1e-8f));
            v.x *= fsc; v.y *= fsc; v.z *= fsc; v.w *= fsc;
            if (pass < 2) {
                // qsum += q_new; each (Kq,ch) owned by exactly one thread
                float* qd = &qsum[Kq * 64 + ch * 4];
                qd[0] += v.x; qd[1] += v.y; qd[2] += v.z; qd[3] += v.w;
            } else {
                *(float4*)(out + (size_t)(b0 + b) * 2048 + Kq * 64 + ch * 4) = v;
            }
        }
        if (pass < 2) __syncthreads();   // qsum visible + qpart reads done
    }
}

extern "C" void kernel_launch(void* const* d_in, const int* in_sizes, int n_in,
                              void* d_out, int out_size, void* d_ws, size_t ws_size,
                              hipStream_t stream) {
    const float* x = (const float*)d_in[0];
    const float* W = (const float*)d_in[1];
    float* out = (float*)d_out;
    float* p   = (float*)d_ws;    // p owns the whole workspace now

    // full batch in one shot if ws >= 128 MiB (R4 proved it is); else 2 chunks
    const int chunk = (ws_size >= (size_t)134217728) ? 256 : 128;

    for (int b0 = 0; b0 < BATCH; b0 += chunk) {
        gemm_kernel<<<dim3(NEXT, PRE, chunk / 128), 256, 0, stream>>>(x, W, p, b0);
        route_kernel<<<chunk, 512, 0, stream>>>(p, out, b0);
    }
}